// Round 1
// baseline (237.262 us; speedup 1.0000x reference)
//
#include <hip/hip_runtime.h>

// PhysicsGuidedAttention: B=2, N=2048, D=768, H=12, Hd=64
//   qkv = x @ w_qkv.T ; attn with elevation bias ; out = attn_out @ w_proj.T + b_proj
// Strategy: bf16 MFMA (16x16x32) for all three GEMM-shaped stages, f32 accum.

typedef __attribute__((ext_vector_type(8))) short bf16x8;   // 8 bf16 = 4 VGPRs
typedef __attribute__((ext_vector_type(4))) float f32x4;    // MFMA accumulator

__device__ __forceinline__ unsigned short f2bf(float f) {
  unsigned int u = __builtin_bit_cast(unsigned int, f);
  u += 0x7fffu + ((u >> 16) & 1u);        // round-to-nearest-even
  return (unsigned short)(u >> 16);
}

// Load 8 consecutive K-elements from row-major [rows, K] source; convert f32->bf16
// if needed; return packed as uint4 (8 bf16).
template<bool F32>
__device__ __forceinline__ uint4 load_pack8(const void* p, size_t off) {
  if constexpr (F32) {
    const float* s = (const float*)p + off;
    float4 f0 = *(const float4*)s;
    float4 f1 = *(const float4*)(s + 4);
    uint4 v;
    v.x = (unsigned)f2bf(f0.x) | ((unsigned)f2bf(f0.y) << 16);
    v.y = (unsigned)f2bf(f0.z) | ((unsigned)f2bf(f0.w) << 16);
    v.z = (unsigned)f2bf(f1.x) | ((unsigned)f2bf(f1.y) << 16);
    v.w = (unsigned)f2bf(f1.z) | ((unsigned)f2bf(f1.w) << 16);
    return v;
  } else {
    return *(const uint4*)((const unsigned short*)p + off);
  }
}

// C[M,N] = A[M,K] @ B[N,K]^T  (both row-major, K contiguous = torch Linear layout)
// 128x128 tile, BK=32, 256 threads = 4 waves in 2x2, each wave 64x64 (4x4 frags).
template<bool A_F32, bool B_F32, bool OUT_F32>
__global__ __launch_bounds__(256)
void gemm_bt_kernel(const void* __restrict__ Ap, const void* __restrict__ Bp,
                    const float* __restrict__ bias, void* __restrict__ Cp,
                    int M, int N, int K) {
  __shared__ __align__(16) unsigned short lds_a[128 * 32];
  __shared__ __align__(16) unsigned short lds_b[128 * 32];
  const int t   = threadIdx.x;
  const int l   = t & 63;
  const int wv  = t >> 6;
  const int wr  = wv >> 1, wc = wv & 1;
  const int brow = blockIdx.x * 128;
  const int bcol = blockIdx.y * 128;
  const int l15 = l & 15, l4 = l >> 4;

  f32x4 acc[4][4] = {};

  const int nk = K >> 5;
  const int c  = (t & 3) * 8;           // k-offset within 32 handled by this thread
  for (int kt = 0; kt < nk; ++kt) {
    uint4 ra[2], rb[2];
    const int k0 = kt * 32 + c;
#pragma unroll
    for (int p = 0; p < 2; ++p) {
      const int r = p * 64 + (t >> 2);
      ra[p] = load_pack8<A_F32>(Ap, (size_t)(brow + r) * K + k0);
      rb[p] = load_pack8<B_F32>(Bp, (size_t)(bcol + r) * K + k0);
    }
    __syncthreads();                     // all waves done reading prev tile
#pragma unroll
    for (int p = 0; p < 2; ++p) {
      const int r = p * 64 + (t >> 2);
      *(uint4*)&lds_a[r * 32 + c] = ra[p];
      *(uint4*)&lds_b[r * 32 + c] = rb[p];
    }
    __syncthreads();
    bf16x8 af[4], bfr[4];
#pragma unroll
    for (int i = 0; i < 4; ++i) {
      af[i]  = *(const bf16x8*)&lds_a[(wr * 64 + i * 16 + l15) * 32 + l4 * 8];
      bfr[i] = *(const bf16x8*)&lds_b[(wc * 64 + i * 16 + l15) * 32 + l4 * 8];
    }
#pragma unroll
    for (int i = 0; i < 4; ++i)
#pragma unroll
      for (int j = 0; j < 4; ++j)
        acc[i][j] = __builtin_amdgcn_mfma_f32_16x16x32_bf16(af[i], bfr[j], acc[i][j], 0, 0, 0);
  }

  // Epilogue. C/D layout: col = lane&15, row = (lane>>4)*4 + reg  [m89-verified]
#pragma unroll
  for (int i = 0; i < 4; ++i)
#pragma unroll
    for (int j = 0; j < 4; ++j)
#pragma unroll
      for (int r = 0; r < 4; ++r) {
        const int row = brow + wr * 64 + i * 16 + l4 * 4 + r;
        const int col = bcol + wc * 64 + j * 16 + l15;
        const float v = acc[i][j][r];
        if constexpr (OUT_F32) {
          ((float*)Cp)[(size_t)row * N + col] = v + bias[col];
        } else {
          ((unsigned short*)Cp)[(size_t)row * N + col] = f2bf(v);
        }
      }
}

// Flash attention with elevation bias.
// grid = (B*H, N/64). 256 threads = 4 waves; wave w owns Q rows [q0+16w, q0+16w+16).
// KV tiles of 64 rows. qkv layout: [B*N, 2304] bf16, q at +0, k at +768, v at +1536,
// head h at +h*64.
__global__ __launch_bounds__(256)
void attn_kernel(const unsigned short* __restrict__ qkv,
                 const float* __restrict__ elev,
                 const float* __restrict__ alpha_p,
                 unsigned short* __restrict__ aout) {
  __shared__ __align__(16) unsigned short lds_k[64 * 64];
  __shared__ __align__(16) unsigned short lds_vt[64 * 64];   // transposed: [d][kv]
  __shared__ __align__(16) unsigned short lds_p[4][16 * 64]; // per-wave P tile
  __shared__ float lds_ej[64];

  const int t = threadIdx.x;
  const int l = t & 63;
  const int w = t >> 6;
  const int l15 = l & 15, l4 = l >> 4;
  const int b = blockIdx.x / 12, h = blockIdx.x % 12;
  const int q0 = blockIdx.y * 64;

  const float alpha = alpha_p[0];
  const float scale = 0.125f;            // 64^-0.5

  const size_t rs = 2304;
  const unsigned short* qbase = qkv + ((size_t)b * 2048) * rs + h * 64;
  const unsigned short* kbase = qbase + 768;
  const unsigned short* vbase = qbase + 1536;

  // Q fragments, held in registers for the whole kernel
  bf16x8 qa[2];
  {
    const int qrow = q0 + w * 16 + l15;
    const unsigned short* qp = qbase + (size_t)qrow * rs + l4 * 8;
    qa[0] = *(const bf16x8*)qp;
    qa[1] = *(const bf16x8*)(qp + 32);
  }
  float ei[4];
#pragma unroll
  for (int r = 0; r < 4; ++r)
    ei[r] = elev[(size_t)b * 2048 + q0 + w * 16 + l4 * 4 + r];

  f32x4 o[4] = {};
  float m_r[4], l_r[4];
#pragma unroll
  for (int r = 0; r < 4; ++r) { m_r[r] = -1e30f; l_r[r] = 0.f; }

  for (int kv0 = 0; kv0 < 2048; kv0 += 64) {
    // --- stage K (row-major) and V (transposed) ---
    uint4 rk[2], rv[2];
    const int c = (t & 7) * 8;
#pragma unroll
    for (int p = 0; p < 2; ++p) {
      const int r = p * 32 + (t >> 3);
      rk[p] = *(const uint4*)(kbase + (size_t)(kv0 + r) * rs + c);
      rv[p] = *(const uint4*)(vbase + (size_t)(kv0 + r) * rs + c);
    }
    __syncthreads();                     // everyone done reading prev K/V tiles
#pragma unroll
    for (int p = 0; p < 2; ++p) {
      const int r = p * 32 + (t >> 3);
      *(uint4*)&lds_k[r * 64 + c] = rk[p];
      union { uint4 u; unsigned short s[8]; } vu; vu.u = rv[p];
#pragma unroll
      for (int j = 0; j < 8; ++j)
        lds_vt[(c + j) * 64 + r] = vu.s[j];   // transpose write
    }
    if (t < 64) lds_ej[t] = elev[(size_t)b * 2048 + kv0 + t];
    __syncthreads();

    // --- S = Q K^T  (16 rows x 64 kv cols per wave) ---
    f32x4 s[4];
#pragma unroll
    for (int nt = 0; nt < 4; ++nt) {
      bf16x8 kb0 = *(const bf16x8*)&lds_k[(nt * 16 + l15) * 64 + l4 * 8];
      bf16x8 kb1 = *(const bf16x8*)&lds_k[(nt * 16 + l15) * 64 + 32 + l4 * 8];
      f32x4 z = {};
      z = __builtin_amdgcn_mfma_f32_16x16x32_bf16(qa[0], kb0, z, 0, 0, 0);
      s[nt] = __builtin_amdgcn_mfma_f32_16x16x32_bf16(qa[1], kb1, z, 0, 0, 0);
    }

    // --- online softmax (rows spread over regs; cols over 16-lane groups) ---
    float pv[4][4];                      // [nt][reg]
#pragma unroll
    for (int r = 0; r < 4; ++r) {
      float sp[4];
      float mx = -1e30f;
#pragma unroll
      for (int nt = 0; nt < 4; ++nt) {
        const float ej = lds_ej[nt * 16 + l15];
        float bias = -alpha * fmaxf((ej - ei[r]) * 1e-3f, 0.f);
        bias = fminf(fmaxf(bias, -10.f), 0.f);
        const float v = s[nt][r] * scale + bias;
        sp[nt] = v;
        mx = fmaxf(mx, v);
      }
#pragma unroll
      for (int off = 1; off < 16; off <<= 1)
        mx = fmaxf(mx, __shfl_xor(mx, off, 64));
      const float mnew = fmaxf(m_r[r], mx);
      const float al = __expf(m_r[r] - mnew);
      float ps = 0.f;
#pragma unroll
      for (int nt = 0; nt < 4; ++nt) {
        const float p = __expf(sp[nt] - mnew);
        pv[nt][r] = p;
        ps += p;
      }
#pragma unroll
      for (int off = 1; off < 16; off <<= 1)
        ps += __shfl_xor(ps, off, 64);
      l_r[r] = l_r[r] * al + ps;
      m_r[r] = mnew;
#pragma unroll
      for (int nt = 0; nt < 4; ++nt)
        o[nt][r] *= al;
    }

    // --- P -> LDS (own wave region), reread in A-frag layout ---
#pragma unroll
    for (int nt = 0; nt < 4; ++nt)
#pragma unroll
      for (int r = 0; r < 4; ++r)
        lds_p[w][(l4 * 4 + r) * 64 + nt * 16 + l15] = f2bf(pv[nt][r]);

    // --- O += P @ V ---
#pragma unroll
    for (int ks = 0; ks < 2; ++ks) {
      bf16x8 pa = *(const bf16x8*)&lds_p[w][l15 * 64 + ks * 32 + l4 * 8];
#pragma unroll
      for (int nt = 0; nt < 4; ++nt) {
        bf16x8 vb = *(const bf16x8*)&lds_vt[(nt * 16 + l15) * 64 + ks * 32 + l4 * 8];
        o[nt] = __builtin_amdgcn_mfma_f32_16x16x32_bf16(pa, vb, o[nt], 0, 0, 0);
      }
    }
  }

  // --- epilogue: O /= l, store bf16 to [B*N, 768] with head-major cols ---
#pragma unroll
  for (int r = 0; r < 4; ++r) {
    const float inv_l = 1.0f / l_r[r];
    const int n = q0 + w * 16 + l4 * 4 + r;
#pragma unroll
    for (int nt = 0; nt < 4; ++nt) {
      const int col = h * 64 + nt * 16 + l15;
      aout[((size_t)b * 2048 + n) * 768 + col] = f2bf(o[nt][r] * inv_l);
    }
  }
}

extern "C" void kernel_launch(void* const* d_in, const int* in_sizes, int n_in,
                              void* d_out, int out_size, void* d_ws, size_t ws_size,
                              hipStream_t stream) {
  const float* x      = (const float*)d_in[0];   // [2,2048,768]
  const float* elev   = (const float*)d_in[1];   // [2,2048]
  const float* w_qkv  = (const float*)d_in[2];   // [2304,768]
  const float* w_proj = (const float*)d_in[3];   // [768,768]
  const float* b_proj = (const float*)d_in[4];   // [768]
  const float* alpha  = (const float*)d_in[5];   // [1]
  float* out = (float*)d_out;                    // [2,2048,768] f32

  unsigned short* qkvb = (unsigned short*)d_ws;            // [4096,2304] bf16
  unsigned short* aob  = qkvb + (size_t)4096 * 2304;       // [4096,768]  bf16

  // 1) qkv = x @ w_qkv^T   (f32 in -> bf16 out)
  gemm_bt_kernel<true, true, false><<<dim3(32, 18), 256, 0, stream>>>(
      x, w_qkv, nullptr, qkvb, 4096, 2304, 768);

  // 2) flash attention with elevation bias  (bf16 -> bf16)
  attn_kernel<<<dim3(24, 32), 256, 0, stream>>>(qkvb, elev, alpha, aob);

  // 3) out = attn_out @ w_proj^T + b_proj   (bf16 in -> f32 out)
  gemm_bt_kernel<false, true, true><<<dim3(32, 6), 256, 0, stream>>>(
      aob, w_proj, b_proj, out, 4096, 768, 768);
}

// Round 2
// 175.870 us; speedup vs baseline: 1.3491x; 1.3491x over previous
//
#include <hip/hip_runtime.h>

// PhysicsGuidedAttention: B=2, N=2048, D=768, H=12, Hd=64
// qkv = x @ w_qkv.T ; flash-attn with elevation bias ; out = attn_out @ w_proj.T + b_proj
// All GEMM-shaped stages: bf16 MFMA 16x16x32, f32 accum.
// R2: XOR-swizzled attn LDS (kills 4.6e7 bank conflicts); bf16 pre-convert +
//     global_load_lds staged GEMMs (m97 structure).

typedef __attribute__((ext_vector_type(8))) short bf16x8;   // 8 bf16 = 4 VGPRs
typedef __attribute__((ext_vector_type(4))) float f32x4;    // MFMA accumulator

__device__ __forceinline__ unsigned short f2bf(float f) {
  unsigned int u = __builtin_bit_cast(unsigned int, f);
  u += 0x7fffu + ((u >> 16) & 1u);        // round-to-nearest-even
  return (unsigned short)(u >> 16);
}

// XOR swizzle on element index (ushort arrays): moves byte bits 4-6.
// row&7 varies on read side (row = ..+l15); row>>3 varies on the vt transpose
// write side (d = (t&7)*8+j). XOR of both spreads every access pattern.
__device__ __forceinline__ int sw8(int row) {
  return ((row ^ (row >> 3)) & 7) << 3;
}

// 16-byte async global->LDS. LDS dest: wave-uniform base + lane*16.
__device__ __forceinline__ void gload16(const unsigned short* g, unsigned short* l) {
  __builtin_amdgcn_global_load_lds(
      (const __attribute__((address_space(1))) unsigned int*)g,
      (__attribute__((address_space(3))) unsigned int*)l, 16, 0, 0);
}

// ---------------------------------------------------------------------------
// f32 -> bf16 convert, 8 elems/thread
__global__ __launch_bounds__(256)
void cvt_kernel(const float* __restrict__ in, unsigned short* __restrict__ out, int n8) {
  const int i = blockIdx.x * 256 + threadIdx.x;
  if (i >= n8) return;
  const float4 f0 = ((const float4*)in)[i * 2];
  const float4 f1 = ((const float4*)in)[i * 2 + 1];
  uint4 v;
  v.x = (unsigned)f2bf(f0.x) | ((unsigned)f2bf(f0.y) << 16);
  v.y = (unsigned)f2bf(f0.z) | ((unsigned)f2bf(f0.w) << 16);
  v.z = (unsigned)f2bf(f1.x) | ((unsigned)f2bf(f1.y) << 16);
  v.w = (unsigned)f2bf(f1.z) | ((unsigned)f2bf(f1.w) << 16);
  ((uint4*)out)[i] = v;
}

// ---------------------------------------------------------------------------
// C[M,N] = A[M,K] @ B[N,K]^T, bf16 inputs, 128x128 tile, BK=32,
// 256 thr = 4 waves (2x2), wave = 64x64 out (4x4 frags of 16x16x32).
// Staging via global_load_lds dwordx4 (m97 structure). BK=32 rows are 64B so
// column-slice ds_read_b128 is already conflict-free (no swizzle needed).
template<bool OUT_F32>
__global__ __launch_bounds__(256)
void gemm_bt_bf16(const unsigned short* __restrict__ Ap,
                  const unsigned short* __restrict__ Bp,
                  const float* __restrict__ bias, void* __restrict__ Cp,
                  int M, int N, int K) {
  __shared__ __align__(16) unsigned short lds_a[128 * 32];
  __shared__ __align__(16) unsigned short lds_b[128 * 32];
  const int t = threadIdx.x;
  const int l = t & 63;
  const int w = t >> 6;
  const int wr = w >> 1, wc = w & 1;
  const int brow = blockIdx.x * 128;
  const int bcol = blockIdx.y * 128;
  const int l15 = l & 15, l4 = l >> 4;

  // staging: thread t covers row t/4 (+64 second half), cols (t&3)*8..+8
  const int srow = t >> 2;
  const int scol = (t & 3) * 8;
  const unsigned short* ga = Ap + (size_t)(brow + srow) * K + scol;
  const unsigned short* gb = Bp + (size_t)(bcol + srow) * K + scol;
  unsigned short* la = lds_a + w * 512;   // wave-uniform; lane*16B implicit
  unsigned short* lb = lds_b + w * 512;

  f32x4 acc[4][4] = {};
  const int nk = K >> 5;
  for (int kt = 0; kt < nk; ++kt) {
    const size_t ko = (size_t)kt * 32;
    gload16(ga + ko, la);
    gload16(ga + ko + (size_t)64 * K, la + 2048);
    gload16(gb + ko, lb);
    gload16(gb + ko + (size_t)64 * K, lb + 2048);
    __syncthreads();                       // drains vmcnt: tiles staged
    bf16x8 af[4], bfr[4];
#pragma unroll
    for (int i = 0; i < 4; ++i) {
      af[i]  = *(const bf16x8*)&lds_a[(wr * 64 + i * 16 + l15) * 32 + l4 * 8];
      bfr[i] = *(const bf16x8*)&lds_b[(wc * 64 + i * 16 + l15) * 32 + l4 * 8];
    }
#pragma unroll
    for (int i = 0; i < 4; ++i)
#pragma unroll
      for (int j = 0; j < 4; ++j)
        acc[i][j] = __builtin_amdgcn_mfma_f32_16x16x32_bf16(af[i], bfr[j], acc[i][j], 0, 0, 0);
    __syncthreads();                       // before next stage overwrites
  }

  // Epilogue. C/D layout: col = lane&15, row = (lane>>4)*4 + reg
#pragma unroll
  for (int i = 0; i < 4; ++i)
#pragma unroll
    for (int j = 0; j < 4; ++j)
#pragma unroll
      for (int r = 0; r < 4; ++r) {
        const int row = brow + wr * 64 + i * 16 + l4 * 4 + r;
        const int col = bcol + wc * 64 + j * 16 + l15;
        const float v = acc[i][j][r];
        if constexpr (OUT_F32) {
          ((float*)Cp)[(size_t)row * N + col] = v + bias[col];
        } else {
          ((unsigned short*)Cp)[(size_t)row * N + col] = f2bf(v);
        }
      }
}

// ---------------------------------------------------------------------------
// Flash attention with elevation bias. grid=(B*H, N/64), 256 thr = 4 waves;
// wave w owns Q rows [q0+16w, q0+16w+16). KV tiles of 64.
// qkv: [B*N, 2304] bf16; q at +0, k at +768, v at +1536, head h at +h*64.
__global__ __launch_bounds__(256)
void attn_kernel(const unsigned short* __restrict__ qkv,
                 const float* __restrict__ elev,
                 const float* __restrict__ alpha_p,
                 unsigned short* __restrict__ aout) {
  __shared__ __align__(16) unsigned short lds_k[64 * 64];
  __shared__ __align__(16) unsigned short lds_vt[64 * 64];   // [d][kv], swizzled
  __shared__ __align__(16) unsigned short lds_p[4][16 * 64]; // per-wave P, swizzled
  __shared__ float lds_ej[64];

  const int t = threadIdx.x;
  const int l = t & 63;
  const int w = t >> 6;
  const int l15 = l & 15, l4 = l >> 4;
  const int b = blockIdx.x / 12, h = blockIdx.x % 12;
  const int q0 = blockIdx.y * 64;

  const float alpha = alpha_p[0];
  const float scale = 0.125f;            // 64^-0.5

  const size_t rs = 2304;
  const unsigned short* qbase = qkv + ((size_t)b * 2048) * rs + h * 64;
  const unsigned short* kbase = qbase + 768;
  const unsigned short* vbase = qbase + 1536;

  bf16x8 qa[2];
  {
    const int qrow = q0 + w * 16 + l15;
    const unsigned short* qp = qbase + (size_t)qrow * rs + l4 * 8;
    qa[0] = *(const bf16x8*)qp;
    qa[1] = *(const bf16x8*)(qp + 32);
  }
  float ei[4];
#pragma unroll
  for (int r = 0; r < 4; ++r)
    ei[r] = elev[(size_t)b * 2048 + q0 + w * 16 + l4 * 4 + r];

  f32x4 o[4] = {};
  float m_r[4], l_r[4];
#pragma unroll
  for (int r = 0; r < 4; ++r) { m_r[r] = -1e30f; l_r[r] = 0.f; }

  for (int kv0 = 0; kv0 < 2048; kv0 += 64) {
    // --- stage K (row-major, swizzled) and V (transposed, swizzled) ---
    uint4 rk[2], rv[2];
    const int c = (t & 7) * 8;
#pragma unroll
    for (int p = 0; p < 2; ++p) {
      const int r = p * 32 + (t >> 3);
      rk[p] = *(const uint4*)(kbase + (size_t)(kv0 + r) * rs + c);
      rv[p] = *(const uint4*)(vbase + (size_t)(kv0 + r) * rs + c);
    }
    __syncthreads();                     // everyone done with prev K/V tiles
#pragma unroll
    for (int p = 0; p < 2; ++p) {
      const int r = p * 32 + (t >> 3);
      *(uint4*)&lds_k[r * 64 + (c ^ sw8(r))] = rk[p];
      union { uint4 u; unsigned short s[8]; } vu; vu.u = rv[p];
#pragma unroll
      for (int j = 0; j < 8; ++j) {
        const int d = c + j;
        lds_vt[d * 64 + (r ^ sw8(d))] = vu.s[j];   // transpose write
      }
    }
    if (t < 64) lds_ej[t] = elev[(size_t)b * 2048 + kv0 + t];
    __syncthreads();

    // --- S = Q K^T  (16 rows x 64 kv cols per wave) ---
    f32x4 s[4];
#pragma unroll
    for (int nt = 0; nt < 4; ++nt) {
      const int kr = nt * 16 + l15;
      bf16x8 kb0 = *(const bf16x8*)&lds_k[kr * 64 + ((l4 * 8) ^ sw8(kr))];
      bf16x8 kb1 = *(const bf16x8*)&lds_k[kr * 64 + ((32 + l4 * 8) ^ sw8(kr))];
      f32x4 z = {};
      z = __builtin_amdgcn_mfma_f32_16x16x32_bf16(qa[0], kb0, z, 0, 0, 0);
      s[nt] = __builtin_amdgcn_mfma_f32_16x16x32_bf16(qa[1], kb1, z, 0, 0, 0);
    }

    // --- online softmax ---
    float pv[4][4];                      // [nt][reg]
#pragma unroll
    for (int r = 0; r < 4; ++r) {
      float sp[4];
      float mx = -1e30f;
#pragma unroll
      for (int nt = 0; nt < 4; ++nt) {
        const float ej = lds_ej[nt * 16 + l15];
        float bias = -alpha * fmaxf((ej - ei[r]) * 1e-3f, 0.f);
        bias = fminf(fmaxf(bias, -10.f), 0.f);
        const float v = s[nt][r] * scale + bias;
        sp[nt] = v;
        mx = fmaxf(mx, v);
      }
#pragma unroll
      for (int off = 1; off < 16; off <<= 1)
        mx = fmaxf(mx, __shfl_xor(mx, off, 64));
      const float mnew = fmaxf(m_r[r], mx);
      const float al = __expf(m_r[r] - mnew);
      float ps = 0.f;
#pragma unroll
      for (int nt = 0; nt < 4; ++nt) {
        const float p = __expf(sp[nt] - mnew);
        pv[nt][r] = p;
        ps += p;
      }
#pragma unroll
      for (int off = 1; off < 16; off <<= 1)
        ps += __shfl_xor(ps, off, 64);
      l_r[r] = l_r[r] * al + ps;
      m_r[r] = mnew;
#pragma unroll
      for (int nt = 0; nt < 4; ++nt)
        o[nt][r] *= al;
    }

    // --- P -> LDS (own wave region, swizzled), reread in A-frag layout ---
#pragma unroll
    for (int nt = 0; nt < 4; ++nt)
#pragma unroll
      for (int r = 0; r < 4; ++r) {
        const int row = l4 * 4 + r;
        lds_p[w][row * 64 + ((nt * 16 + l15) ^ sw8(row))] = f2bf(pv[nt][r]);
      }

    // --- O += P @ V ---
#pragma unroll
    for (int ks = 0; ks < 2; ++ks) {
      bf16x8 pa = *(const bf16x8*)&lds_p[w][l15 * 64 + ((ks * 32 + l4 * 8) ^ sw8(l15))];
#pragma unroll
      for (int nt = 0; nt < 4; ++nt) {
        const int d = nt * 16 + l15;
        bf16x8 vb = *(const bf16x8*)&lds_vt[d * 64 + ((ks * 32 + l4 * 8) ^ sw8(d))];
        o[nt] = __builtin_amdgcn_mfma_f32_16x16x32_bf16(pa, vb, o[nt], 0, 0, 0);
      }
    }
  }

  // --- epilogue ---
#pragma unroll
  for (int r = 0; r < 4; ++r) {
    const float inv_l = 1.0f / l_r[r];
    const int n = q0 + w * 16 + l4 * 4 + r;
#pragma unroll
    for (int nt = 0; nt < 4; ++nt) {
      const int col = h * 64 + nt * 16 + l15;
      aout[((size_t)b * 2048 + n) * 768 + col] = f2bf(o[nt][r] * inv_l);
    }
  }
}

extern "C" void kernel_launch(void* const* d_in, const int* in_sizes, int n_in,
                              void* d_out, int out_size, void* d_ws, size_t ws_size,
                              hipStream_t stream) {
  const float* x      = (const float*)d_in[0];   // [2,2048,768]
  const float* elev   = (const float*)d_in[1];   // [2,2048]
  const float* w_qkv  = (const float*)d_in[2];   // [2304,768]
  const float* w_proj = (const float*)d_in[3];   // [768,768]
  const float* b_proj = (const float*)d_in[4];   // [768]
  const float* alpha  = (const float*)d_in[5];   // [1]
  float* out = (float*)d_out;                    // [2,2048,768] f32

  // ws layout (bf16): [qkvb 4096x2304][xb 4096x768 -> reused as aob][wqkvb -> reused as wprojb]
  unsigned short* qkvb   = (unsigned short*)d_ws;
  unsigned short* xb     = qkvb + (size_t)4096 * 2304;
  unsigned short* aob    = xb;                          // reuse after gemm1
  unsigned short* wqkvb  = xb + (size_t)4096 * 768;
  unsigned short* wprojb = wqkvb;                       // reuse after gemm1

  // converts
  cvt_kernel<<<(4096 * 768 / 8 + 255) / 256, 256, 0, stream>>>(x, xb, 4096 * 768 / 8);
  cvt_kernel<<<(2304 * 768 / 8 + 255) / 256, 256, 0, stream>>>(w_qkv, wqkvb, 2304 * 768 / 8);

  // 1) qkv = x @ w_qkv^T  (bf16 out)
  gemm_bt_bf16<false><<<dim3(32, 18), 256, 0, stream>>>(
      xb, wqkvb, nullptr, qkvb, 4096, 2304, 768);

  cvt_kernel<<<(768 * 768 / 8 + 255) / 256, 256, 0, stream>>>(w_proj, wprojb, 768 * 768 / 8);

  // 2) flash attention with elevation bias
  attn_kernel<<<dim3(24, 32), 256, 0, stream>>>(qkvb, elev, alpha, aob);

  // 3) out = attn_out @ w_proj^T + b_proj  (f32 out + bias)
  gemm_bt_bf16<true><<<dim3(32, 6), 256, 0, stream>>>(
      aob, wprojb, b_proj, out, 4096, 768, 768);
}

// Round 3
// 127.569 us; speedup vs baseline: 1.8599x; 1.3786x over previous
//
#include <hip/hip_runtime.h>

// PhysicsGuidedAttention: B=2, N=2048, D=768, H=12, Hd=64
// qkv = x @ w_qkv.T ; flash-attn with elevation bias ; out = attn_out @ w_proj.T + b_proj
// R3: attn rebuilt on 32x32x16 MFMA, swapped QK^T (S^T = K x Q), no-max log2-domain
//     softmax (input-bounded), P kept in registers via cvt_pk + permlane32_swap,
//     double-buffered K/V^T with split staging.

typedef __attribute__((ext_vector_type(8))) short bf16x8;   // 8 bf16 = 4 VGPRs
typedef __attribute__((ext_vector_type(4))) float f32x4;
typedef __attribute__((ext_vector_type(16))) float f32x16;  // 32x32 accumulator

__device__ __forceinline__ unsigned short f2bf(float f) {
  unsigned int u = __builtin_bit_cast(unsigned int, f);
  u += 0x7fffu + ((u >> 16) & 1u);        // round-to-nearest-even
  return (unsigned short)(u >> 16);
}

__device__ __forceinline__ unsigned cvtpk(float lo, float hi) {
  unsigned r;
  asm("v_cvt_pk_bf16_f32 %0, %1, %2" : "=v"(r) : "v"(lo), "v"(hi));
  return r;
}

__device__ __forceinline__ float exp2v(float x) {
  float r;
  asm("v_exp_f32 %0, %1" : "=v"(r) : "v"(x));
  return r;
}

// XOR swizzle on element index: spreads 128B-stride row starts across banks.
__device__ __forceinline__ int sw8(int row) {
  return ((row ^ (row >> 3)) & 7) << 3;
}

__device__ __forceinline__ void gload16(const unsigned short* g, unsigned short* l) {
  __builtin_amdgcn_global_load_lds(
      (const __attribute__((address_space(1))) unsigned int*)g,
      (__attribute__((address_space(3))) unsigned int*)l, 16, 0, 0);
}

// ---------------------------------------------------------------------------
__global__ __launch_bounds__(256)
void cvt_kernel(const float* __restrict__ in, unsigned short* __restrict__ out, int n8) {
  const int i = blockIdx.x * 256 + threadIdx.x;
  if (i >= n8) return;
  const float4 f0 = ((const float4*)in)[i * 2];
  const float4 f1 = ((const float4*)in)[i * 2 + 1];
  uint4 v;
  v.x = (unsigned)f2bf(f0.x) | ((unsigned)f2bf(f0.y) << 16);
  v.y = (unsigned)f2bf(f0.z) | ((unsigned)f2bf(f0.w) << 16);
  v.z = (unsigned)f2bf(f1.x) | ((unsigned)f2bf(f1.y) << 16);
  v.w = (unsigned)f2bf(f1.z) | ((unsigned)f2bf(f1.w) << 16);
  ((uint4*)out)[i] = v;
}

// ---------------------------------------------------------------------------
// C[M,N] = A[M,K] @ B[N,K]^T, bf16, 128x128 tile, BK=32 (unchanged from R2).
template<bool OUT_F32>
__global__ __launch_bounds__(256)
void gemm_bt_bf16(const unsigned short* __restrict__ Ap,
                  const unsigned short* __restrict__ Bp,
                  const float* __restrict__ bias, void* __restrict__ Cp,
                  int M, int N, int K) {
  __shared__ __align__(16) unsigned short lds_a[128 * 32];
  __shared__ __align__(16) unsigned short lds_b[128 * 32];
  const int t = threadIdx.x;
  const int l = t & 63;
  const int w = t >> 6;
  const int wr = w >> 1, wc = w & 1;
  const int brow = blockIdx.x * 128;
  const int bcol = blockIdx.y * 128;
  const int l15 = l & 15, l4 = l >> 4;

  const int srow = t >> 2;
  const int scol = (t & 3) * 8;
  const unsigned short* ga = Ap + (size_t)(brow + srow) * K + scol;
  const unsigned short* gb = Bp + (size_t)(bcol + srow) * K + scol;
  unsigned short* la = lds_a + w * 512;
  unsigned short* lb = lds_b + w * 512;

  f32x4 acc[4][4] = {};
  const int nk = K >> 5;
  for (int kt = 0; kt < nk; ++kt) {
    const size_t ko = (size_t)kt * 32;
    gload16(ga + ko, la);
    gload16(ga + ko + (size_t)64 * K, la + 2048);
    gload16(gb + ko, lb);
    gload16(gb + ko + (size_t)64 * K, lb + 2048);
    __syncthreads();
    bf16x8 af[4], bfr[4];
#pragma unroll
    for (int i = 0; i < 4; ++i) {
      af[i]  = *(const bf16x8*)&lds_a[(wr * 64 + i * 16 + l15) * 32 + l4 * 8];
      bfr[i] = *(const bf16x8*)&lds_b[(wc * 64 + i * 16 + l15) * 32 + l4 * 8];
    }
#pragma unroll
    for (int i = 0; i < 4; ++i)
#pragma unroll
      for (int j = 0; j < 4; ++j)
        acc[i][j] = __builtin_amdgcn_mfma_f32_16x16x32_bf16(af[i], bfr[j], acc[i][j], 0, 0, 0);
    __syncthreads();
  }

#pragma unroll
  for (int i = 0; i < 4; ++i)
#pragma unroll
    for (int j = 0; j < 4; ++j)
#pragma unroll
      for (int r = 0; r < 4; ++r) {
        const int row = brow + wr * 64 + i * 16 + l4 * 4 + r;
        const int col = bcol + wc * 64 + j * 16 + l15;
        const float v = acc[i][j][r];
        if constexpr (OUT_F32) {
          ((float*)Cp)[(size_t)row * N + col] = v + bias[col];
        } else {
          ((unsigned short*)Cp)[(size_t)row * N + col] = f2bf(v);
        }
      }
}

// ---------------------------------------------------------------------------
// Flash attention, 32x32x16 MFMA, swapped QK^T, no max-tracking.
// grid = (B*H, N/128); 256 thr = 4 waves; wave w owns q rows [q0+32w, q0+32w+32).
// KV tiles of 64, double-buffered.
// S^T = mfma(A=K, B=Q): lane col = q (l&31); C rows kv = (r&3)+8(r>>2)+4h (+32mb).
// PV A-frag built in-register: cvt_pk pairs + v_permlane32_swap_b32.
__global__ __launch_bounds__(256)
void attn_kernel(const unsigned short* __restrict__ qkv,
                 const float* __restrict__ elev,
                 const float* __restrict__ alpha_p,
                 unsigned short* __restrict__ aout) {
  __shared__ __align__(16) unsigned short lds_k[2][64 * 64];
  __shared__ __align__(16) unsigned short lds_vt[2][64 * 64];   // [d][kv], swizzled
  __shared__ __align__(16) float lds_ej[2][64];                 // pre-scaled elev
  __shared__ __align__(16) float lds_linv[4][32];

  const int t = threadIdx.x;
  const int l = t & 63;
  const int w = t >> 6;
  const int l31 = l & 31;
  const int h = l >> 5;
  const int b = blockIdx.x / 12, hd = blockIdx.x % 12;
  const int q0 = blockIdx.y * 128 + w * 32;

  // exp domain: exp2. cE folds alpha/1000*log2e into elevation; c1 = scale*log2e.
  const float cE = fmaxf(alpha_p[0], 0.f) * (1.4426950408889634f * 1e-3f);
  const float c1 = 0.18033688011112042f;   // 0.125 * log2(e)

  const size_t rs = 2304;
  const unsigned short* qbase = qkv + ((size_t)b * 2048) * rs + hd * 64;
  const unsigned short* kbase = qbase + 768;
  const unsigned short* vbase = qbase + 1536;

  // Q: lane holds its own q-row (q0+l31), d-slices 16*ks + 8*h .. +8
  bf16x8 qa[4];
  {
    const unsigned short* qp = qbase + (size_t)(q0 + l31) * rs + h * 8;
#pragma unroll
    for (int ks = 0; ks < 4; ++ks) qa[ks] = *(const bf16x8*)(qp + ks * 16);
  }
  const float eiv = elev[(size_t)b * 2048 + q0 + l31] * cE;

  f32x16 o[2] = {};
  float psum = 0.f;

  const int sr = t >> 3;          // staging row 0..31
  const int sc = (t & 7) * 8;     // staging col

  uint4 rk[2], rv[2];
  float evn = 0.f;

  // prologue: stage tile 0
#pragma unroll
  for (int p = 0; p < 2; ++p) {
    const int r = p * 32 + sr;
    rk[p] = *(const uint4*)(kbase + (size_t)r * rs + sc);
    rv[p] = *(const uint4*)(vbase + (size_t)r * rs + sc);
  }
  if (t < 64) evn = elev[(size_t)b * 2048 + t];
#pragma unroll
  for (int p = 0; p < 2; ++p) {
    const int r = p * 32 + sr;
    *(uint4*)&lds_k[0][r * 64 + (sc ^ sw8(r))] = rk[p];
    union { uint4 u; unsigned short s[8]; } vu; vu.u = rv[p];
#pragma unroll
    for (int j = 0; j < 8; ++j) {
      const int d = sc + j;
      lds_vt[0][d * 64 + (r ^ sw8(d))] = vu.s[j];
    }
  }
  if (t < 64) lds_ej[0][t] = evn * cE;
  __syncthreads();

  for (int it = 0; it < 32; ++it) {
    const int cur = it & 1;
    const bool more = it < 31;
    if (more) {
      const int kv1 = (it + 1) * 64;
#pragma unroll
      for (int p = 0; p < 2; ++p) {
        const int r = kv1 + p * 32 + sr;
        rk[p] = *(const uint4*)(kbase + (size_t)r * rs + sc);
        rv[p] = *(const uint4*)(vbase + (size_t)r * rs + sc);
      }
      if (t < 64) evn = elev[(size_t)b * 2048 + kv1 + t];
    }

    // --- S^T = K x Q ---
    f32x16 st[2] = {};
    __builtin_amdgcn_s_setprio(1);
#pragma unroll
    for (int kst = 0; kst < 4; ++kst) {
      const int col = kst * 16 + h * 8;
#pragma unroll
      for (int mb = 0; mb < 2; ++mb) {
        const int row = mb * 32 + l31;
        bf16x8 kf = *(const bf16x8*)&lds_k[cur][row * 64 + (col ^ sw8(row))];
        st[mb] = __builtin_amdgcn_mfma_f32_32x32x16_bf16(kf, qa[kst], st[mb], 0, 0, 0);
      }
    }
    __builtin_amdgcn_s_setprio(0);

    // --- softmax (no max-tracking) + in-register P pack ---
    // lane's reg r of mb holds S^T[kv = 32mb + (r&3)+8(r>>2)+4h][q = q0+l31]
    bf16x8 pa[4];
#pragma unroll
    for (int mb = 0; mb < 2; ++mb) {
      float p16[16];
#pragma unroll
      for (int rr = 0; rr < 4; ++rr) {
        const float4 ejq = *(const float4*)&lds_ej[cur][mb * 32 + rr * 8 + h * 4];
#pragma unroll
        for (int jl = 0; jl < 4; ++jl) {
          const int r = rr * 4 + jl;
          const float bm = __builtin_amdgcn_fmed3f(ejq[jl] - eiv, 0.f, 14.4269504f);
          const float p = exp2v(__builtin_fmaf(st[mb][r], c1, -bm));
          p16[r] = p;
          psum += p;
        }
      }
      // build A-frags for PV: frag ks = 2*mb + ks2 holds kv = 16ks + 8h + j
#pragma unroll
      for (int ks2 = 0; ks2 < 2; ++ks2) {
        unsigned u0 = cvtpk(p16[ks2 * 8 + 0], p16[ks2 * 8 + 1]);
        unsigned u1 = cvtpk(p16[ks2 * 8 + 2], p16[ks2 * 8 + 3]);
        unsigned v0 = cvtpk(p16[ks2 * 8 + 4], p16[ks2 * 8 + 5]);
        unsigned v1 = cvtpk(p16[ks2 * 8 + 6], p16[ks2 * 8 + 7]);
        asm volatile("v_permlane32_swap_b32 %0, %1" : "+v"(u0), "+v"(v0));
        asm volatile("v_permlane32_swap_b32 %0, %1" : "+v"(u1), "+v"(v1));
        uint4 fr; fr.x = u0; fr.y = u1; fr.z = v0; fr.w = v1;
        pa[mb * 2 + ks2] = __builtin_bit_cast(bf16x8, fr);
      }
    }

    // --- O += P @ V ---
    __builtin_amdgcn_s_setprio(1);
#pragma unroll
    for (int ks = 0; ks < 4; ++ks) {
      const int col = ks * 16 + h * 8;
#pragma unroll
      for (int nb = 0; nb < 2; ++nb) {
        const int row = nb * 32 + l31;
        bf16x8 vf = *(const bf16x8*)&lds_vt[cur][row * 64 + (col ^ sw8(row))];
        o[nb] = __builtin_amdgcn_mfma_f32_32x32x16_bf16(pa[ks], vf, o[nb], 0, 0, 0);
      }
    }
    __builtin_amdgcn_s_setprio(0);

    // --- write next tile ---
    if (more) {
      const int nxt = cur ^ 1;
#pragma unroll
      for (int p = 0; p < 2; ++p) {
        const int r = p * 32 + sr;
        *(uint4*)&lds_k[nxt][r * 64 + (sc ^ sw8(r))] = rk[p];
        union { uint4 u; unsigned short s[8]; } vu; vu.u = rv[p];
#pragma unroll
        for (int j = 0; j < 8; ++j) {
          const int d = sc + j;
          lds_vt[nxt][d * 64 + (r ^ sw8(d))] = vu.s[j];
        }
      }
      if (t < 64) lds_ej[nxt][t] = evn * cE;
      __syncthreads();
    }
  }

  // --- epilogue: l = psum(h0)+psum(h1); O /= l; store bf16 ---
  psum += __shfl_xor(psum, 32, 64);
  if (h == 0) lds_linv[w][l31] = 1.0f / psum;
  __syncthreads();

#pragma unroll
  for (int nb = 0; nb < 2; ++nb) {
    const int col = hd * 64 + nb * 32 + l31;
#pragma unroll
    for (int rr = 0; rr < 4; ++rr) {
      const float4 lq = *(const float4*)&lds_linv[w][rr * 8 + h * 4];
#pragma unroll
      for (int jl = 0; jl < 4; ++jl) {
        const int q = q0 + rr * 8 + h * 4 + jl;
        aout[((size_t)b * 2048 + q) * 768 + col] = f2bf(o[nb][rr * 4 + jl] * lq[jl]);
      }
    }
  }
}

extern "C" void kernel_launch(void* const* d_in, const int* in_sizes, int n_in,
                              void* d_out, int out_size, void* d_ws, size_t ws_size,
                              hipStream_t stream) {
  const float* x      = (const float*)d_in[0];   // [2,2048,768]
  const float* elev   = (const float*)d_in[1];   // [2,2048]
  const float* w_qkv  = (const float*)d_in[2];   // [2304,768]
  const float* w_proj = (const float*)d_in[3];   // [768,768]
  const float* b_proj = (const float*)d_in[4];   // [768]
  const float* alpha  = (const float*)d_in[5];   // [1]
  float* out = (float*)d_out;                    // [2,2048,768] f32

  unsigned short* qkvb   = (unsigned short*)d_ws;
  unsigned short* xb     = qkvb + (size_t)4096 * 2304;
  unsigned short* aob    = xb;                          // reuse after gemm1
  unsigned short* wqkvb  = xb + (size_t)4096 * 768;
  unsigned short* wprojb = wqkvb;                       // reuse after gemm1

  cvt_kernel<<<(4096 * 768 / 8 + 255) / 256, 256, 0, stream>>>(x, xb, 4096 * 768 / 8);
  cvt_kernel<<<(2304 * 768 / 8 + 255) / 256, 256, 0, stream>>>(w_qkv, wqkvb, 2304 * 768 / 8);

  gemm_bt_bf16<false><<<dim3(32, 18), 256, 0, stream>>>(
      xb, wqkvb, nullptr, qkvb, 4096, 2304, 768);

  cvt_kernel<<<(768 * 768 / 8 + 255) / 256, 256, 0, stream>>>(w_proj, wprojb, 768 * 768 / 8);

  attn_kernel<<<dim3(24, 16), 256, 0, stream>>>(qkvb, elev, alpha, aob);

  gemm_bt_bf16<true><<<dim3(32, 6), 256, 0, stream>>>(
      aob, wprojb, b_proj, out, 4096, 768, 768);
}